// Round 8
// baseline (40.737 us; speedup 1.0000x reference)
//
#include <hip/hip_runtime.h>
#include <stdint.h>

#define HH 64
#define WW 64
#define PIN 64
#define POUT 64
#define NFEAT 54
#define NPH 27

typedef _Float16 half8 __attribute__((ext_vector_type(8)));
typedef _Float16 half4 __attribute__((ext_vector_type(4)));
typedef float f32x4 __attribute__((ext_vector_type(4)));
typedef float f32x16 __attribute__((ext_vector_type(16)));

// feature enumeration tables: f -> (k,l), matching prep_filters order
__constant__ const int KT[54] = {0,0,0,0,0,0,0,0,0, 1,1,1,1,1,1,1,1,1, 2,2,2,2,2,2,2,2,
                                 3,3,3,3,3,3,3, 4,4,4,4,4,4, 5,5,5,5,5, 6,6,6,6, 7,7,7, 8,8, 9};
__constant__ const int LT[54] = {1,2,3,4,5,6,7,8,9, 1,2,3,4,5,6,7,8,9, 2,3,4,5,6,7,8,9,
                                 3,4,5,6,7,8,9, 4,5,6,7,8,9, 5,6,7,8,9, 6,7,8,9, 7,8,9, 8,9, 9};

// ---------------- filter prep ----------------
// Fprep[f][o][c] fp16; Fconst[o] = bias + sum_c F[o,c,0,0]. 8 parts per feature.
__global__ void prep_filters(const float* __restrict__ f, const float* __restrict__ bias,
                             _Float16* __restrict__ fprep, float* __restrict__ fconst) {
    int blk = blockIdx.x;
    if (blk == NFEAT * 8) {
        int o = threadIdx.x;
        if (o < POUT) {
            float s = bias[o];
            for (int c = 0; c < PIN; ++c) s += f[(size_t)(o * PIN + c) * 100];
            fconst[o] = s;
        }
        return;
    }
    int feat = blk >> 3, part = blk & 7;
    int k = 0, l = 0, cnt = 0;
    for (int kk = 0; kk <= 9; ++kk) {
        int ls = (kk == 0) ? 1 : kk;
        for (int ll = ls; ll <= 9; ++ll) {
            if (cnt == feat) { k = kk; l = ll; }
            ++cnt;
        }
    }
    int iend = (part + 1) * 512;
    for (int i = part * 512 + threadIdx.x; i < iend; i += 256) {
        int o = i >> 6, c = i & 63;
        const float* fc = f + (size_t)(o * PIN + c) * 100;
        float v;
        if (k == 0)      v = fc[l] + fc[l * 10];
        else if (k == l) v = fc[k * 10 + k];
        else             v = fc[k * 10 + l] + fc[l * 10 + k];
        fprep[((size_t)feat * POUT + o) * PIN + c] = (_Float16)v;
    }
}

// barrier that the compiler cannot move memory ops across
__device__ __forceinline__ void blockbar() {
    asm volatile("" ::: "memory");
    __builtin_amdgcn_s_barrier();
    asm volatile("" ::: "memory");
}

// ---------------- main MFMA kernel ----------------
// grid 512 = b(8) x hrow(64), XCD-swizzled; block 512 thr = 8 waves =
// 2 m-tiles (32 px) x 4 kc-quarters (K=16). MFMA 32x32x16_f16.
// B via 3-slot LDS ring, 2 features/phase (16KB slots), counted vmcnt.
// LDS 74.5KB -> 2 blocks/CU so phase barriers overlap across blocks.
__global__ __launch_bounds__(512, 4) void poly2d_mfma(
    const float* __restrict__ x, const _Float16* __restrict__ fprep,
    const float* __restrict__ fconst, float* __restrict__ out)
{
    __shared__ __align__(16) char smx[25344];     // x tile [3][66][8cg swz][16B]; reused as os[64][65] f32
    __shared__ __align__(16) char ring[3 * 16384]; // B ring: slot = 2 features x 8KB

    const int t = threadIdx.x;
    const int lane = t & 63;
    const int wid = t >> 6;            // 0..7
    // XCD-bijective swizzle (512 % 8 == 0): each XCD gets 64 consecutive rows of one batch
    const int bid = (blockIdx.x & 7) * 64 + (blockIdx.x >> 3);
    const int b = bid >> 6;
    const int hrow = bid & 63;

    // ---- stage x tile (rows hrow-1..hrow+1, wl 0..65, 64 c) as swizzled fp16 ----
    {
        const int w = t & 63;
        const int wl = w + 1;
        #pragma unroll
        for (int h = 0; h < 3; ++h) {
            int h_in = hrow - 1 + h;
            bool hok = ((unsigned)h_in < HH);
            #pragma unroll
            for (int cc = 0; cc < 2; ++cc) {
                int c = wid * 8 + cc * 4;  // channels c..c+3
                float v0 = 0.f, v1 = 0.f, v2 = 0.f, v3 = 0.f;
                if (hok) {
                    const float* gx = x + (((size_t)b * PIN + c) * HH + h_in) * WW + w;
                    v0 = gx[0]; v1 = gx[4096]; v2 = gx[8192]; v3 = gx[12288];
                }
                half4 pk = {(_Float16)v0, (_Float16)v1, (_Float16)v2, (_Float16)v3};
                int byte = ((h * 66 + wl) * 8 + ((c >> 3) ^ (wl & 7))) * 16 + (c & 7) * 2;
                *(half4*)(smx + byte) = pk;
            }
        }
        if (t < 48) { // w halo: wl=0 and wl=65 out of image -> zero. 3 rows x 2 sides x 8 cg
            int h = t >> 4, side = (t >> 3) & 1, cg = t & 7;
            int wl2 = side ? 65 : 0;
            int byte = ((h * 66 + wl2) * 8 + (cg ^ (wl2 & 7))) * 16;
            f32x4 z = {0.f, 0.f, 0.f, 0.f};
            *(f32x4*)(smx + byte) = z;
        }
    }
    __syncthreads(); // drains vmcnt: clean baseline for manual counting

    const int kc = wid >> 1;           // 0..3 channel quarter
    const int mwid = wid & 1;          // m-tile (w-half)
    const int wbase = mwid * 32;
    const int l31 = lane & 31;
    const int lhi = lane >> 5;         // 0/1

    // stager source permutation (all 8 waves; one feature = 512 chunks of 16B):
    // chunk (wid,lane) <-> o = l31 + (wid&1)*32, kc-quarter = (wid>>1)&3, half = lhi
    const int o_s = l31 + ((wid & 1) << 5);
    const int j16 = o_s * 128 + ((wid >> 1) & 3) * 32 + lhi * 16;
    const char* gsrc = (const char*)fprep + j16;

#define STAGE(ff, ph)                                                                     \
    __builtin_amdgcn_global_load_lds(                                                     \
        (const __attribute__((address_space(1))) unsigned int*)(const void*)(gsrc + (size_t)(ff) * 8192), \
        (__attribute__((address_space(3))) unsigned int*)(void*)(ring + ((ph) % 3) * 16384 + ((ff) & 1) * 8192 + (wid << 10)), \
        16, 0, 0)

    // prologue: stage phases 0 and 1 (features 0..3): 4 loads/thread outstanding
    STAGE(0, 0); STAGE(1, 0); STAGE(2, 1); STAGE(3, 1);

    // ---- load 9 shift panels (A-frag: row=lane&31 -> pixel, k=(lane>>5)*8+j) ----
    half8 xp[9];
    #pragma unroll
    for (int p = 1; p <= 9; ++p) {
        const int dh = (p - 1) / 3 - 1, dw = (p - 1) % 3 - 1;
        int wl = wbase + l31 + dw + 1;
        int hidx = dh + 1;
        int cgl = kc * 2 + lhi;
        int byte = ((hidx * 66 + wl) * 8 + (cgl ^ (wl & 7))) * 16;
        xp[p - 1] = *(const half8*)(smx + byte);
    }

    f32x16 acc0 = {}, acc1 = {};

    #pragma unroll
    for (int ph = 0; ph < NPH; ++ph) {
        // barrier 1: my ds_reads of phase ph-1 retired before its slot is restaged
        asm volatile("s_waitcnt lgkmcnt(0)" ::: "memory");
        blockbar();
        if (ph + 2 < NPH) { STAGE(2 * (ph + 2), ph + 2); STAGE(2 * (ph + 2) + 1, ph + 2); }
        // counted wait for phase ph's 2 loads (never drain in steady state)
        if (ph < NPH - 2)       asm volatile("s_waitcnt vmcnt(4)" ::: "memory");
        else if (ph == NPH - 2) asm volatile("s_waitcnt vmcnt(2)" ::: "memory");
        else                    asm volatile("s_waitcnt vmcnt(0)" ::: "memory");
        blockbar(); // barrier 2: whole slot present

        #pragma unroll
        for (int pp = 0; pp < 2; ++pp) {
            const int f = ph * 2 + pp;
            const int k = KT[f], l = LT[f];
            const char* bbase = ring + (ph % 3) * 16384 + pp * 8192 + (kc << 11) + (lane << 4);
            half8 b0 = *(const half8*)(bbase);
            half8 b1 = *(const half8*)(bbase + 1024);
            half8 a = (k == 0) ? xp[l - 1] : xp[k - 1] * xp[l - 1];
            acc0 = __builtin_amdgcn_mfma_f32_32x32x16_f16(a, b0, acc0, 0, 0, 0);
            acc1 = __builtin_amdgcn_mfma_f32_32x32x16_f16(a, b1, acc1, 0, 0, 0);
        }
    }
#undef STAGE

    __syncthreads(); // loop done; x-region free for output staging
    float* os = (float*)smx; // [64 px][65]

    // reduce 4 kc partials (C/D: col=lane&31 (+nb*32), row=(r&3)+8*(r>>2)+4*lhi)
    #pragma unroll
    for (int pass = 0; pass < 4; ++pass) {
        if (kc == pass) {
            #pragma unroll
            for (int nb = 0; nb < 2; ++nb) {
                #pragma unroll
                for (int r = 0; r < 16; ++r) {
                    int row = (r & 3) + 8 * (r >> 2) + 4 * lhi;
                    int m = mwid * 32 + row;
                    int col = l31 + nb * 32;
                    float v = nb ? acc1[r] : acc0[r];
                    if (pass == 0) os[m * 65 + col] = v;
                    else           os[m * 65 + col] += v;
                }
            }
        }
        __syncthreads();
    }

    { // coalesced store: lanes sweep w
        const int w = t & 63;
        #pragma unroll
        for (int oo = 0; oo < 8; ++oo) {
            int o = wid * 8 + oo;
            float val = os[w * 65 + o] + fconst[o];
            out[(((size_t)b * POUT + o) * HH + hrow) * WW + w] = val;
        }
    }
}

// ---------------- fp32 fallback, used only if ws too small ----------------
__global__ __launch_bounds__(256) void poly2d_fp32(
    const float* __restrict__ x, const float* __restrict__ f,
    const float* __restrict__ bias, float* __restrict__ out)
{
    const int t = threadIdx.x;
    const int wo = t & 63;
    const int ho = (blockIdx.x & 15) * 4 + (t >> 6);
    const int o = (blockIdx.x >> 4) & 63;
    const int b = blockIdx.x >> 10;

    float acc = bias[o];
    const float* xb = x + (size_t)b * PIN * HH * WW;
    const float* fo = f + (size_t)o * PIN * 100;
    for (int c = 0; c < PIN; ++c) {
        const float* xc = xb + (size_t)c * HH * WW;
        float s[10];
        s[0] = 1.0f;
        #pragma unroll
        for (int kh = 0; kh < 3; ++kh) {
            int h = ho - 1 + kh;
            bool hok = ((unsigned)h < HH);
            #pragma unroll
            for (int kw = 0; kw < 3; ++kw) {
                int w = wo - 1 + kw;
                s[1 + kh * 3 + kw] = (hok && (unsigned)w < WW) ? xc[h * WW + w] : 0.0f;
            }
        }
        const float* fc = fo + c * 100;
        #pragma unroll
        for (int i = 0; i < 10; ++i) {
            float wsum = 0.0f;
            #pragma unroll
            for (int j = 0; j < 10; ++j) wsum = fmaf(fc[i * 10 + j], s[j], wsum);
            acc = fmaf(wsum, s[i], acc);
        }
    }
    out[(((size_t)b * POUT + o) * HH + ho) * WW + wo] = acc;
}

extern "C" void kernel_launch(void* const* d_in, const int* in_sizes, int n_in,
                              void* d_out, int out_size, void* d_ws, size_t ws_size,
                              hipStream_t stream) {
    const float* x    = (const float*)d_in[0];
    const float* filt = (const float*)d_in[1];
    const float* bias = (const float*)d_in[2];
    float* out = (float*)d_out;

    const size_t FPREP_BYTES = (size_t)NFEAT * POUT * PIN * 2; // 442368
    if (ws_size < FPREP_BYTES + 256) {
        poly2d_fp32<<<dim3(8 * 64 * 16), dim3(256), 0, stream>>>(x, filt, bias, out);
        return;
    }
    _Float16* fprep = (_Float16*)d_ws;
    float* fconst = (float*)((char*)d_ws + FPREP_BYTES);

    prep_filters<<<dim3(NFEAT * 8 + 1), dim3(256), 0, stream>>>(filt, bias, fprep, fconst);
    poly2d_mfma<<<dim3(512), dim3(512), 0, stream>>>(x, fprep, fconst, out);
}